// Round 2
// baseline (1410.215 us; speedup 1.0000x reference)
//
#include <hip/hip_runtime.h>
#include <hip/hip_bf16.h>
#include <cstdint>
#include <cstddef>

#define NMAT 4096

typedef __bf16 bf16x8 __attribute__((ext_vector_type(8)));
typedef float f32x4 __attribute__((ext_vector_type(4)));

__device__ inline float fastrcp(float x) { return __builtin_amdgcn_rcpf(x); }

// ---------- prep: row max + exp + bf16 store; init v1 = 1.0, v0 = 0.0 ----------
__global__ __launch_bounds__(256) void prep_kernel(const float* __restrict__ M,
                                                   __bf16* __restrict__ m0,
                                                   float* __restrict__ v1,
                                                   float* __restrict__ v0z) {
    const int row = blockIdx.x, t = threadIdx.x;
    if (blockIdx.x < 16) v1[blockIdx.x * 256 + t] = 1.0f;
    else if (blockIdx.x < 32) v0z[(blockIdx.x - 16) * 256 + t] = 0.0f;
    const float4* rp = (const float4*)(M + (size_t)row * NMAT);
    float4 p[4];
#pragma unroll
    for (int s = 0; s < 4; s++) p[s] = rp[t * 4 + s];
    float mx = -1e30f;
#pragma unroll
    for (int s = 0; s < 4; s++)
        mx = fmaxf(mx, fmaxf(fmaxf(p[s].x, p[s].y), fmaxf(p[s].z, p[s].w)));
#pragma unroll
    for (int off = 32; off; off >>= 1) mx = fmaxf(mx, __shfl_down(mx, off));
    __shared__ float wm[4];
    if ((t & 63) == 0) wm[t >> 6] = mx;
    __syncthreads();
    mx = fmaxf(fmaxf(wm[0], wm[1]), fmaxf(wm[2], wm[3]));
    bf16x8 o[2];
#pragma unroll
    for (int s = 0; s < 4; s++) {
        o[s >> 1][(s & 1) * 4 + 0] = (__bf16)__expf(0.5f * (p[s].x - mx));
        o[s >> 1][(s & 1) * 4 + 1] = (__bf16)__expf(0.5f * (p[s].y - mx));
        o[s >> 1][(s & 1) * 4 + 2] = (__bf16)__expf(0.5f * (p[s].z - mx));
        o[s >> 1][(s & 1) * 4 + 3] = (__bf16)__expf(0.5f * (p[s].w - mx));
    }
    bf16x8* op = (bf16x8*)(m0 + (size_t)row * NMAT + t * 16);
    op[0] = o[0];
    op[1] = o[1];
}

// ---------- L = sigmoid(5*lower) * tril, bf16 ----------
__global__ __launch_bounds__(256) void lmask_kernel(const float* __restrict__ Lo,
                                                    __bf16* __restrict__ Lm) {
    const int row = blockIdx.x, t = threadIdx.x;
    const float4* rp = (const float4*)(Lo + (size_t)row * NMAT);
    bf16x8 o[2];
#pragma unroll
    for (int s = 0; s < 4; s++) {
        float4 p = rp[t * 4 + s];
        int c0 = t * 16 + s * 4;
        float f0 = (c0 + 0 <= row) ? fastrcp(1.f + __expf(-5.f * p.x)) : 0.f;
        float f1 = (c0 + 1 <= row) ? fastrcp(1.f + __expf(-5.f * p.y)) : 0.f;
        float f2 = (c0 + 2 <= row) ? fastrcp(1.f + __expf(-5.f * p.z)) : 0.f;
        float f3 = (c0 + 3 <= row) ? fastrcp(1.f + __expf(-5.f * p.w)) : 0.f;
        o[s >> 1][(s & 1) * 4 + 0] = (__bf16)f0;
        o[s >> 1][(s & 1) * 4 + 1] = (__bf16)f1;
        o[s >> 1][(s & 1) * 4 + 2] = (__bf16)f2;
        o[s >> 1][(s & 1) * 4 + 3] = (__bf16)f3;
    }
    bf16x8* op = (bf16x8*)(Lm + (size_t)row * NMAT + t * 16);
    op[0] = o[0];
    op[1] = o[1];
}

// ---------- fused Sinkhorn iteration ----------
// Block owns 16 rows. Pass 1: u_i = sum_j m0[i,j] * (1/vprev[j]) (rows cached to LDS).
// Pass 2: atomicAdd(vnew_j, m0[i,j] * (1/u_i)) from LDS. Also zeroes vzero (buffer
// for NEXT iteration) and writes raw u. One global matrix read per iteration.
__global__ __launch_bounds__(1024) void sinkhorn_iter(const __bf16* __restrict__ m0,
                                                      const float* __restrict__ vprev,
                                                      float* __restrict__ vnew,
                                                      float* __restrict__ vzero,
                                                      float* __restrict__ u) {
    __shared__ float cs[NMAT];       // 16 KiB: 1/vprev
    __shared__ float ws[16];         // 1/u for the block's rows
    __shared__ __bf16 mrows[16][NMAT];  // 128 KiB: the block's 16 rows
    const int t = threadIdx.x, blk = blockIdx.x;
    if (t < 16) vzero[blk * 16 + t] = 0.0f;
#pragma unroll
    for (int s = 0; s < 4; s++) {
        int j = s * 1024 + t;
        cs[j] = fastrcp(vprev[j]);
    }
    __syncthreads();
    const int wave = t >> 6, lane = t & 63;
    const int row = blk * 16 + wave;
    const __bf16* rp = m0 + (size_t)row * NMAT;
    float sum = 0.f;
#pragma unroll
    for (int jj = 0; jj < NMAT; jj += 512) {
        int j = jj + lane * 8;
        bf16x8 mv = *(const bf16x8*)(rp + j);
        *(bf16x8*)&mrows[wave][j] = mv;
        float4 c0 = *(const float4*)(cs + j);
        float4 c1 = *(const float4*)(cs + j + 4);
        sum += (float)mv[0] * c0.x + (float)mv[1] * c0.y + (float)mv[2] * c0.z +
               (float)mv[3] * c0.w + (float)mv[4] * c1.x + (float)mv[5] * c1.y +
               (float)mv[6] * c1.z + (float)mv[7] * c1.w;
    }
#pragma unroll
    for (int off = 32; off; off >>= 1) sum += __shfl_down(sum, off);
    if (lane == 0) {
        u[row] = sum;               // raw u (final iter feeds invvec)
        ws[wave] = fastrcp(sum);
    }
    __syncthreads();
    // pass 2: column partials over this block's 16 rows
    const int col = t * 4;
    float a0 = 0.f, a1 = 0.f, a2 = 0.f, a3 = 0.f;
#pragma unroll
    for (int i = 0; i < 16; i++) {
        const float wi = ws[i];
        ushort4 mv = *(const ushort4*)&mrows[i][col];
        a0 += wi * __uint_as_float((unsigned)mv.x << 16);
        a1 += wi * __uint_as_float((unsigned)mv.y << 16);
        a2 += wi * __uint_as_float((unsigned)mv.z << 16);
        a3 += wi * __uint_as_float((unsigned)mv.w << 16);
    }
    atomicAdd(vnew + col + 0, a0);
    atomicAdd(vnew + col + 1, a1);
    atomicAdd(vnew + col + 2, a2);
    atomicAdd(vnew + col + 3, a3);
}

// ---------- r = 1/u (in place); c = 1/v ----------
__global__ __launch_bounds__(256) void invvec_kernel(float* __restrict__ u,
                                                     const float* __restrict__ v,
                                                     float* __restrict__ c) {
    const int i = blockIdx.x * 256 + threadIdx.x;
    u[i] = fastrcp(u[i]);
    c[i] = fastrcp(v[i]);
}

// ---------- m[i,j] = m0[i,j] * r_i * c_j (in place, bf16) ----------
__global__ __launch_bounds__(256) void rescale_kernel(__bf16* __restrict__ m,
                                                      const float* __restrict__ r,
                                                      const float* __restrict__ c) {
    const int row = blockIdx.x, t = threadIdx.x;
    const float rr = r[row];
    bf16x8* mp = (bf16x8*)(m + (size_t)row * NMAT + t * 16);
    bf16x8 a = mp[0], b = mp[1];
    const float4* cp = (const float4*)(c + t * 16);
    float4 c0 = cp[0], c1 = cp[1], c2 = cp[2], c3 = cp[3];
    bf16x8 oa, ob;
    oa[0] = (__bf16)(rr * c0.x * (float)a[0]);
    oa[1] = (__bf16)(rr * c0.y * (float)a[1]);
    oa[2] = (__bf16)(rr * c0.z * (float)a[2]);
    oa[3] = (__bf16)(rr * c0.w * (float)a[3]);
    oa[4] = (__bf16)(rr * c1.x * (float)a[4]);
    oa[5] = (__bf16)(rr * c1.y * (float)a[5]);
    oa[6] = (__bf16)(rr * c1.z * (float)a[6]);
    oa[7] = (__bf16)(rr * c1.w * (float)a[7]);
    ob[0] = (__bf16)(rr * c2.x * (float)b[0]);
    ob[1] = (__bf16)(rr * c2.y * (float)b[1]);
    ob[2] = (__bf16)(rr * c2.z * (float)b[2]);
    ob[3] = (__bf16)(rr * c2.w * (float)b[3]);
    ob[4] = (__bf16)(rr * c3.x * (float)b[4]);
    ob[5] = (__bf16)(rr * c3.y * (float)b[5]);
    ob[6] = (__bf16)(rr * c3.z * (float)b[6]);
    ob[7] = (__bf16)(rr * c3.w * (float)b[7]);
    mp[0] = oa;
    mp[1] = ob;
}

// ---------- NT GEMM: C[i,j] = sum_k A[i,k]*B[j,k] ----------
// 256x256 tile, BK=32, 4 LDS buffers (lookahead-3 prefetch), 512 threads (8 waves 2x4),
// counted vmcnt, raw s_barrier + lgkmcnt, setprio MFMA clusters, and T2 quarter-XOR
// LDS swizzle (both-sides: pre-swizzled global source + swizzled ds_read; rule #21).
template <int OUTBF>
__global__ __launch_bounds__(512, 2) void gemm_nt(const __bf16* __restrict__ A,
                                                  const __bf16* __restrict__ B,
                                                  void* __restrict__ C) {
    __shared__ __bf16 lds[4 * 16384];
    const int t = threadIdx.x;
    const int lane = t & 63, wave = t >> 6;
    const int wm = wave >> 2, wn = wave & 3;   // 2 x 4 wave grid
    const int fr = lane & 15, fq = lane >> 4;  // MFMA fragment coords
    // swizzled fragment byte-quarter: fq ^ ((row>>1)&3); row bits 1-2 == fr bits 1-2
    const int fs = (fq ^ ((fr >> 1) & 3)) * 8;

    // XCD-aware bijective block swizzle: 256 blocks, 8 XCDs
    const int bid = blockIdx.y * 16 + blockIdx.x;
    const int wg = (bid & 7) * 32 + (bid >> 3);
    const int bi = (wg >> 4) * 256;
    const int bj = (wg & 15) * 256;

    // staging: lane l covers (row = l>>2, quarter = l&3) of a 16-row x 64B chunk.
    // Source pre-swizzle: quarter' = (l&3) ^ ((row>>1)&3)  (involution per chunk).
    const int srow = lane >> 2;
    const int scol = ((lane & 3) ^ ((srow >> 1) & 3)) * 8;
    const int sub = wave * 2;

    f32x4 acc[8][4];
#pragma unroll
    for (int m = 0; m < 8; m++)
#pragma unroll
        for (int n = 0; n < 4; n++) acc[m][n] = (f32x4){0.f, 0.f, 0.f, 0.f};

    auto stageA = [&](int kt, int buf) {
#pragma unroll
        for (int q = 0; q < 2; q++) {
            const int row = (sub + q) * 16 + srow;
            const __bf16* g = A + (size_t)(bi + row) * NMAT + kt * 32 + scol;
            char* l = (char*)lds + buf * 32768 + (sub + q) * 1024;
            __builtin_amdgcn_global_load_lds(
                (__attribute__((address_space(1))) void*)g,
                (__attribute__((address_space(3))) void*)l, 16, 0, 0);
        }
    };
    auto stageB = [&](int kt, int buf) {
#pragma unroll
        for (int q = 0; q < 2; q++) {
            const int row = (sub + q) * 16 + srow;
            const __bf16* g = B + (size_t)(bj + row) * NMAT + kt * 32 + scol;
            char* l = (char*)lds + buf * 32768 + 16384 + (sub + q) * 1024;
            __builtin_amdgcn_global_load_lds(
                (__attribute__((address_space(1))) void*)g,
                (__attribute__((address_space(3))) void*)l, 16, 0, 0);
        }
    };

    stageA(0, 0); stageB(0, 0);
    stageA(1, 1); stageB(1, 1);
    stageA(2, 2); stageB(2, 2);
    asm volatile("s_waitcnt vmcnt(8)" ::: "memory");
    __builtin_amdgcn_s_barrier();

    const int NK = NMAT / 32;  // 128
    for (int kt = 0; kt < NK; ++kt) {
        const __bf16* bufA = lds + (kt & 3) * 16384;
        const __bf16* bufB = bufA + 8192;
        const int sb = (kt + 3) & 3;
        const bool dstage = (kt + 3) < NK;

        // ---- phase 0: ds_read B (4) + A lower half (4); issue A prefetch ----
        bf16x8 bfr[4], af0[4];
#pragma unroll
        for (int n = 0; n < 4; n++)
            bfr[n] = *(const bf16x8*)(bufB + (wn * 64 + n * 16 + fr) * 32 + fs);
#pragma unroll
        for (int m = 0; m < 4; m++)
            af0[m] = *(const bf16x8*)(bufA + (wm * 128 + m * 16 + fr) * 32 + fs);
        if (dstage) stageA(kt + 3, sb);
        __builtin_amdgcn_s_barrier();
        asm volatile("s_waitcnt lgkmcnt(0)" ::: "memory");
        __builtin_amdgcn_sched_barrier(0);
        __builtin_amdgcn_s_setprio(1);
#pragma unroll
        for (int m = 0; m < 4; m++)
#pragma unroll
            for (int n = 0; n < 4; n++)
                acc[m][n] = __builtin_amdgcn_mfma_f32_16x16x32_bf16(af0[m], bfr[n],
                                                                    acc[m][n], 0, 0, 0);
        __builtin_amdgcn_s_setprio(0);
        __builtin_amdgcn_sched_barrier(0);

        // ---- phase 1: ds_read A upper half (4); issue B prefetch ----
        bf16x8 af1[4];
#pragma unroll
        for (int m = 0; m < 4; m++)
            af1[m] = *(const bf16x8*)(bufA + (wm * 128 + (m + 4) * 16 + fr) * 32 + fs);
        if (dstage) stageB(kt + 3, sb);
        __builtin_amdgcn_s_barrier();
        asm volatile("s_waitcnt lgkmcnt(0)" ::: "memory");
        __builtin_amdgcn_sched_barrier(0);
        __builtin_amdgcn_s_setprio(1);
#pragma unroll
        for (int m = 0; m < 4; m++)
#pragma unroll
            for (int n = 0; n < 4; n++)
                acc[m + 4][n] = __builtin_amdgcn_mfma_f32_16x16x32_bf16(af1[m], bfr[n],
                                                                        acc[m + 4][n], 0, 0, 0);
        __builtin_amdgcn_s_setprio(0);
        __builtin_amdgcn_sched_barrier(0);

        if (kt + 3 < NK) {
            asm volatile("s_waitcnt vmcnt(8)" ::: "memory");
        } else if (kt + 2 < NK) {
            asm volatile("s_waitcnt vmcnt(4)" ::: "memory");
        } else if (kt + 1 < NK) {
            asm volatile("s_waitcnt vmcnt(0)" ::: "memory");
        }
        __builtin_amdgcn_s_barrier();
    }

#pragma unroll
    for (int m = 0; m < 8; m++)
#pragma unroll
        for (int n = 0; n < 4; n++) {
            const int orow = bi + wm * 128 + m * 16 + fq * 4;
            const int ocol = bj + wn * 64 + n * 16 + fr;
            if (OUTBF) {
                __bf16* o = (__bf16*)C;
#pragma unroll
                for (int e = 0; e < 4; e++)
                    o[(size_t)(orow + e) * NMAT + ocol] = (__bf16)acc[m][n][e];
            } else {
                float* o = (float*)C;
#pragma unroll
                for (int e = 0; e < 4; e++)
                    o[(size_t)(orow + e) * NMAT + ocol] = acc[m][n][e];
            }
        }
}

extern "C" void kernel_launch(void* const* d_in, const int* in_sizes, int n_in,
                              void* d_out, int out_size, void* d_ws, size_t ws_size,
                              hipStream_t stream) {
    (void)in_sizes; (void)n_in; (void)out_size; (void)ws_size;
    const float* matrix = (const float*)d_in[0];
    const float* lower = (const float*)d_in[1];
    float* out = (float*)d_out;
    char* ws = (char*)d_ws;

    __bf16* m0 = (__bf16*)ws;                                // 32 MiB
    __bf16* Lm = (__bf16*)(ws + (size_t)33554432);           // 32 MiB
    __bf16* T1 = (__bf16*)(ws + (size_t)67108864);           // 32 MiB (free during loop)
    float* u   = (float*)(ws + (size_t)100663296);           // 16 KiB
    float* v0  = (float*)(ws + (size_t)100679680);           // 16 KiB
    float* v1  = (float*)(ws + (size_t)100696064);           // 16 KiB
    float* v2  = (float*)(ws + (size_t)67108864);            // 16 KiB, aliases T1 (dead then)

    prep_kernel<<<NMAT, 256, 0, stream>>>(matrix, m0, v1, v0);
    lmask_kernel<<<NMAT, 256, 0, stream>>>(lower, Lm);

    // 3-buffer rotation: it reads vb[it%3], atomics into vb[(it+1)%3], zeroes vb[(it+2)%3]
    float* vb[3] = {v1, v0, v2};
    for (int it = 0; it < 20; ++it) {
        sinkhorn_iter<<<256, 1024, 0, stream>>>(m0, vb[it % 3], vb[(it + 1) % 3],
                                                vb[(it + 2) % 3], u);
    }
    // final: u raw, v_final = vb[20%3] = v2
    invvec_kernel<<<16, 256, 0, stream>>>(u, v2, v0);     // u <- 1/u, v0 <- 1/v2
    rescale_kernel<<<NMAT, 256, 0, stream>>>(m0, u, v0);  // m0 <- diag(r) m0 diag(c)

    gemm_nt<1><<<dim3(16, 16), 512, 0, stream>>>(m0, Lm, (void*)T1);   // T1 = m L^T
    gemm_nt<0><<<dim3(16, 16), 512, 0, stream>>>(T1, m0, (void*)out);  // out = T1 m^T
}